// Round 1
// baseline (104.611 us; speedup 1.0000x reference)
//
#include <hip/hip_runtime.h>

// GraphPool: out[s,a,f] = max over {self, valid neighbors} atoms[s,idx,f],
// zeroed when the atom has no valid neighbors (all edges == -1).
// S=512, A=128, F=128, D=6.

constexpr int S = 512;
constexpr int A = 128;
constexpr int F = 128;
constexpr int D = 6;

__global__ __launch_bounds__(256) void graphpool_kernel(
    const float* __restrict__ atoms,   // (S, A, F)
    const int*   __restrict__ edges,   // (S, A, D), -1 = padding
    float*       __restrict__ out)     // (S, A, F)
{
    // 32 threads per atom, each handles 4 features (float4). 8 atoms/block.
    const int tid           = threadIdx.x;
    const int lane_f        = tid & 31;        // feature quad index 0..31
    const int atom_in_block = tid >> 5;        // 0..7
    const int global_atom   = blockIdx.x * 8 + atom_in_block;  // 0..S*A-1

    const int s = global_atom >> 7;   // / A
    const int a = global_atom & 127;  // % A

    const float* atom_slab = atoms + (size_t)s * (A * F);
    const int*   e         = edges + (size_t)global_atom * D;

    // Self feature initializes the max (include_self=True in reference).
    const float4* self_ptr = (const float4*)(atom_slab + a * F) + lane_f;
    float4 m = *self_ptr;

    int degree = 0;
#pragma unroll
    for (int d = 0; d < D; ++d) {
        int idx = e[d];
        if (idx >= 0) {
            ++degree;
            float4 v = *((const float4*)(atom_slab + idx * F) + lane_f);
            m.x = fmaxf(m.x, v.x);
            m.y = fmaxf(m.y, v.y);
            m.z = fmaxf(m.z, v.z);
            m.w = fmaxf(m.w, v.w);
        }
    }

    if (degree == 0) {
        m = make_float4(0.f, 0.f, 0.f, 0.f);
    }

    float4* out_ptr = (float4*)(out + (size_t)global_atom * F) + lane_f;
    *out_ptr = m;
}

extern "C" void kernel_launch(void* const* d_in, const int* in_sizes, int n_in,
                              void* d_out, int out_size, void* d_ws, size_t ws_size,
                              hipStream_t stream) {
    const float* atoms = (const float*)d_in[0];
    const int*   edges = (const int*)d_in[1];
    float*       out   = (float*)d_out;

    const int total_atoms = S * A;          // 65536
    const int atoms_per_block = 8;
    const int grid = total_atoms / atoms_per_block;  // 8192

    graphpool_kernel<<<grid, 256, 0, stream>>>(atoms, edges, out);
}

// Round 2
// 85.392 us; speedup vs baseline: 1.2251x; 1.2251x over previous
//
#include <hip/hip_runtime.h>

// GraphPool: out[s,a,f] = max over {self, valid neighbors} atoms[s,idx,f],
// zeroed when atom has no valid neighbors. S=512, A=128, F=128, D=6.
//
// Strategy: one block per (s, feature-half). Stage the 128x64 f32 half-slab
// (row-padded to 68 floats -> deterministically uniform LDS bank traffic for
// the gather) plus the 128x6 edge table in LDS, then each thread gathers one
// float4 feature quad per atom, 8 atoms per thread. Branch-free: -1 edges
// remap to the self row (identity under max).

constexpr int S = 512;
constexpr int A = 128;
constexpr int F = 128;
constexpr int D = 6;
constexpr int ROW = 68;          // 64 floats + 4 pad -> bank start = 4*idx % 32

__global__ __launch_bounds__(256, 4) void graphpool_kernel(
    const float* __restrict__ atoms,   // (S, A, F)
    const int*   __restrict__ edges,   // (S, A, D), -1 = padding
    float*       __restrict__ out)     // (S, A, F)
{
    __shared__ float sl[A * ROW];      // 34816 B
    __shared__ int   se[A * D];        // 3072 B   (total 37888 B -> 4 blocks/CU)

    const int tid = threadIdx.x;
    const int h   = blockIdx.x & 1;    // feature half: cols h*64 .. h*64+63
    const int s   = blockIdx.x >> 1;

    // ---- stage atoms half-slab (coalesced 256B chunks per row) ----
    const float* slab = atoms + (size_t)s * (A * F) + h * 64;
#pragma unroll
    for (int i = tid; i < A * 16; i += 256) {       // 2048 float4-slots, 8 iters
        const int r = i >> 4;                       // row 0..127
        const int c = i & 15;                       // quad 0..15
        float4 v = *(const float4*)(slab + r * F + c * 4);
        *(float4*)(&sl[r * ROW + c * 4]) = v;
    }
    // ---- stage edge table ----
    const int* eg = edges + (size_t)s * (A * D);
#pragma unroll
    for (int i = tid; i < A * D; i += 256)          // 768 ints, 3 iters
        se[i] = eg[i];

    __syncthreads();

    const int q = tid & 15;                         // feature quad within half
    float* out_base = out + (size_t)s * (A * F) + h * 64 + q * 4;

#pragma unroll
    for (int pass = 0; pass < 8; ++pass) {
        const int a = (pass << 4) + (tid >> 4);     // atom 0..127

        // self initializes the running max (include_self=True)
        float4 m = *(const float4*)(&sl[a * ROW + q * 4]);

        int deg = 0;
#pragma unroll
        for (int d = 0; d < D; ++d) {
            int idx = se[a * D + d];
            deg += (idx >= 0);
            int ridx = (idx >= 0) ? idx : a;        // -1 -> self (identity)
            float4 v = *(const float4*)(&sl[ridx * ROW + q * 4]);
            m.x = fmaxf(m.x, v.x);
            m.y = fmaxf(m.y, v.y);
            m.z = fmaxf(m.z, v.z);
            m.w = fmaxf(m.w, v.w);
        }
        if (deg == 0) m = make_float4(0.f, 0.f, 0.f, 0.f);

        *(float4*)(out_base + a * F) = m;
    }
}

extern "C" void kernel_launch(void* const* d_in, const int* in_sizes, int n_in,
                              void* d_out, int out_size, void* d_ws, size_t ws_size,
                              hipStream_t stream) {
    const float* atoms = (const float*)d_in[0];
    const int*   edges = (const int*)d_in[1];
    float*       out   = (float*)d_out;

    graphpool_kernel<<<S * 2, 256, 0, stream>>>(atoms, edges, out);
}

// Round 3
// 83.113 us; speedup vs baseline: 1.2587x; 1.0274x over previous
//
#include <hip/hip_runtime.h>
#include <stdint.h>

// GraphPool: out[s,a,f] = max over {self, valid neighbors} atoms[s,idx,f],
// zeroed when atom has no valid neighbors. S=512, A=128, F=128, D=6.
//
// One block per (s, feature-quarter): stage the 128x32 f32 slab via
// global_load_lds (async, width=16, unpadded rows -> bank-uniform b128
// gather), precompute per-atom gather BYTE offsets + validity mask once,
// then a lean gather loop: 9 ds_read_b128 + fmax per pass.

constexpr int S  = 512;
constexpr int A  = 128;
constexpr int F  = 128;
constexpr int D  = 6;
constexpr int QF = 32;              // features per block
constexpr int ROWB = QF * 4;        // LDS row bytes = 128

#define GLOBAL_AS __attribute__((address_space(1)))
#define LDS_AS    __attribute__((address_space(3)))

__global__ __launch_bounds__(256, 8) void graphpool_kernel(
    const float* __restrict__ atoms,   // (S, A, F)
    const int*   __restrict__ edges,   // (S, A, D), -1 = padding
    float*       __restrict__ out)     // (S, A, F)
{
    __shared__ __align__(16) float sl[A * QF];  // 16 KB
    __shared__ __align__(16) int   se[A * 8];   // 4 KB: off0..off5, maskbits, pad

    const int tid  = threadIdx.x;
    const int qb   = blockIdx.x & 3;            // feature quarter
    const int s    = blockIdx.x >> 2;
    const int wave = tid >> 6;
    const int lane = tid & 63;

    // ---- async stage atoms quarter-slab: 16 chunks of 1 KB, 4 per wave ----
    // chunk = 8 rows x 32 floats; lane l -> row l>>3, quad col l&7;
    // LDS dest = uniform chunk base + 16*lane (global_load_lds contract).
    const float* slab = atoms + (size_t)s * (A * F) + qb * QF;
    {
        const int rowq = lane >> 3;
        const int colq = lane & 7;
#pragma unroll
        for (int i = 0; i < 4; ++i) {
            const int chunk = wave * 4 + i;
            const float* gp = slab + (size_t)(chunk * 8 + rowq) * F + colq * 4;
            float* lp = &sl[chunk * 256];       // wave-uniform base
            __builtin_amdgcn_global_load_lds((const GLOBAL_AS float*)gp,
                                             (LDS_AS float*)lp, 16, 0, 0);
        }
    }

    // ---- edge precompute: thread t < 128 handles atom t ----
    if (tid < A) {
        const int* eg = edges + ((size_t)s * A + tid) * D;
        const int i0 = eg[0], i1 = eg[1], i2 = eg[2];
        const int i3 = eg[3], i4 = eg[4], i5 = eg[5];
        const int deg = (i0 >= 0) + (i1 >= 0) + (i2 >= 0) +
                        (i3 >= 0) + (i4 >= 0) + (i5 >= 0);
        const int self = tid * ROWB;            // byte offset of own row
        int4 w0, w1;
        w0.x = (i0 >= 0) ? i0 * ROWB : self;
        w0.y = (i1 >= 0) ? i1 * ROWB : self;
        w0.z = (i2 >= 0) ? i2 * ROWB : self;
        w0.w = (i3 >= 0) ? i3 * ROWB : self;
        w1.x = (i4 >= 0) ? i4 * ROWB : self;
        w1.y = (i5 >= 0) ? i5 * ROWB : self;
        w1.z = __float_as_int(deg ? 1.0f : 0.0f);
        w1.w = 0;
        *(int4*)&se[tid * 8]     = w0;
        *(int4*)&se[tid * 8 + 4] = w1;
    }

    __syncthreads();   // drains vmcnt (global_load_lds) + lgkmcnt

    // ---- gather: 256 threads x 4 passes cover 128 atoms x 8 quads ----
    const int q    = tid & 7;
    const int qoff = q * 16;                    // byte offset within row
    const char* lbase = (const char*)sl;
    float* outb = out + (size_t)s * (A * F) + qb * QF + q * 4;

#pragma unroll
    for (int p = 0; p < 4; ++p) {
        const int a = p * 32 + (tid >> 3);

        const int4 e0 = *(const int4*)&se[a * 8];
        const int4 e1 = *(const int4*)&se[a * 8 + 4];
        const float maskf = __int_as_float(e1.z);

        float4 m = *(const float4*)(lbase + a * ROWB + qoff);  // self
        float4 v;
        v = *(const float4*)(lbase + e0.x + qoff);
        m.x = fmaxf(m.x, v.x); m.y = fmaxf(m.y, v.y);
        m.z = fmaxf(m.z, v.z); m.w = fmaxf(m.w, v.w);
        v = *(const float4*)(lbase + e0.y + qoff);
        m.x = fmaxf(m.x, v.x); m.y = fmaxf(m.y, v.y);
        m.z = fmaxf(m.z, v.z); m.w = fmaxf(m.w, v.w);
        v = *(const float4*)(lbase + e0.z + qoff);
        m.x = fmaxf(m.x, v.x); m.y = fmaxf(m.y, v.y);
        m.z = fmaxf(m.z, v.z); m.w = fmaxf(m.w, v.w);
        v = *(const float4*)(lbase + e0.w + qoff);
        m.x = fmaxf(m.x, v.x); m.y = fmaxf(m.y, v.y);
        m.z = fmaxf(m.z, v.z); m.w = fmaxf(m.w, v.w);
        v = *(const float4*)(lbase + e1.x + qoff);
        m.x = fmaxf(m.x, v.x); m.y = fmaxf(m.y, v.y);
        m.z = fmaxf(m.z, v.z); m.w = fmaxf(m.w, v.w);
        v = *(const float4*)(lbase + e1.y + qoff);
        m.x = fmaxf(m.x, v.x); m.y = fmaxf(m.y, v.y);
        m.z = fmaxf(m.z, v.z); m.w = fmaxf(m.w, v.w);

        m.x *= maskf; m.y *= maskf; m.z *= maskf; m.w *= maskf;

        *(float4*)(outb + (size_t)a * F) = m;
    }
}

extern "C" void kernel_launch(void* const* d_in, const int* in_sizes, int n_in,
                              void* d_out, int out_size, void* d_ws, size_t ws_size,
                              hipStream_t stream) {
    const float* atoms = (const float*)d_in[0];
    const int*   edges = (const int*)d_in[1];
    float*       out   = (float*)d_out;

    graphpool_kernel<<<S * 4, 256, 0, stream>>>(atoms, edges, out);
}